// Round 3
// baseline (1411.611 us; speedup 1.0000x reference)
//
#include <hip/hip_runtime.h>
#include <hip/hip_bf16.h>
#include <math.h>

// Problem constants
#define BB 8
#define CC 64
#define NN 4096
#define CO 64
#define KK 20
#define SPLIT 8
#define BN (BB*NN)           // 32768 rows
#define CN (CC*NN)           // 262144
#define EPSV 1e-5
#define NEG_SLOPE 0.2f
#define CNT_TOTAL 655360.0   // B*N*K
#define EQCAP 16

// Workspace layout (bytes)
#define OFF_P1    ((size_t)0)          // BN*64 f32 = 8388608
#define OFF_P2    ((size_t)8388608)    // 8388608
#define OFF_XX    ((size_t)16777216)   // BN f32 = 131072
#define OFF_IDX   ((size_t)16908288)   // BN*20 i32 = 2621440
#define OFF_TVALS ((size_t)19529728)   // BN*160 f32 = 20971520  layout [s*20+k][row]
#define OFF_T19   ((size_t)40501248)   // BN f32 = 131072
#define OFF_EQB   ((size_t)40632320)   // BN*16 i32 = 2097152
#define OFF_MAXH  ((size_t)42729472)   // 8388608
#define OFF_MINH  ((size_t)51118080)   // 8388608
#define OFF_GCNT  ((size_t)59506688)   // BN i32 = 131072   (zeroed)
#define OFF_ECNT  ((size_t)59637760)   // BN i32 = 131072   (zeroed)
#define OFF_SUMS  ((size_t)59768832)   // 128 f64 = 1024    (zeroed)
#define ZERO_BYTES (131072 + 131072 + 1024)

// Shared dot: FIXED fmaf DAG so k2a and k2c produce bitwise-identical d.
__device__ __forceinline__ float dot_d(const float4* xi, const float* rowp,
                                       float xxi, float xxj) {
  const float4* row = (const float4*)rowp;
  float a0 = 0.f, a1 = 0.f, a2 = 0.f, a3 = 0.f;
#pragma unroll
  for (int c4 = 0; c4 < 16; ++c4) {
    const float4 v = row[c4];
    a0 = fmaf(xi[c4].x, v.x, a0);
    a1 = fmaf(xi[c4].y, v.y, a1);
    a2 = fmaf(xi[c4].z, v.z, a2);
    a3 = fmaf(xi[c4].w, v.w, a3);
  }
  return 2.f*((a0 + a1) + (a2 + a3)) - xxi - xxj;
}

// ---------------- K1: per-point projections p1=(W1-W2)x, p2=W2 x, xx=|x|^2
__global__ __launch_bounds__(256) void k1_project(
    const float* __restrict__ x, const float* __restrict__ W,
    float* __restrict__ p1, float* __restrict__ p2, float* __restrict__ xx) {
  const int b  = blockIdx.y;
  const int n0 = blockIdx.x * 64;
  const int t  = threadIdx.x;
  const int pos = t & 63, og = t >> 6;
  const int n = n0 + pos;
  const float* xb = x + (size_t)b*CN + n;

  float a1[16], a2[16];
#pragma unroll
  for (int i = 0; i < 16; ++i) { a1[i] = 0.f; a2[i] = 0.f; }
  float xxa = 0.f;

#pragma unroll
  for (int c4 = 0; c4 < 16; ++c4) {
    float xv[4];
#pragma unroll
    for (int u = 0; u < 4; ++u) xv[u] = xb[(size_t)(c4*4+u)*NN];
    if (og == 0) xxa += xv[0]*xv[0] + xv[1]*xv[1] + xv[2]*xv[2] + xv[3]*xv[3];
#pragma unroll
    for (int oi = 0; oi < 16; ++oi) {
      const int o = og*16 + oi;
      const float4 w1 = *(const float4*)(W + o*128 + c4*4);
      const float4 w2 = *(const float4*)(W + o*128 + 64 + c4*4);
      a1[oi] += (w1.x - w2.x)*xv[0] + (w1.y - w2.y)*xv[1]
              + (w1.z - w2.z)*xv[2] + (w1.w - w2.w)*xv[3];
      a2[oi] += w2.x*xv[0] + w2.y*xv[1] + w2.z*xv[2] + w2.w*xv[3];
    }
  }
  float* p1o = p1 + ((size_t)(b*NN + n))*64 + og*16;
  float* p2o = p2 + ((size_t)(b*NN + n))*64 + og*16;
#pragma unroll
  for (int oi = 0; oi < 16; ++oi) { p1o[oi] = a1[oi]; p2o[oi] = a2[oi]; }
  if (og == 0) xx[b*NN + n] = xxa;
}

// ---------------- K2a: distances + branchless sorted top-20 VALUES per split
__global__ __launch_bounds__(256) void k2a_vals(
    const float* __restrict__ x, const float* __restrict__ xx,
    float* __restrict__ tvals) {
  __shared__ float xjt[128*68];
  __shared__ float xxj[128];
  const int b = blockIdx.z;
  const int s = blockIdx.y;
  const int t = threadIdx.x;
  const int i = blockIdx.x*256 + t;
  const float* xb = x + (size_t)b*CN;

  float4 xi[16];
#pragma unroll
  for (int c4 = 0; c4 < 16; ++c4) {
    xi[c4].x = xb[(size_t)(c4*4+0)*NN + i];
    xi[c4].y = xb[(size_t)(c4*4+1)*NN + i];
    xi[c4].z = xb[(size_t)(c4*4+2)*NN + i];
    xi[c4].w = xb[(size_t)(c4*4+3)*NN + i];
  }
  const float xxi = xx[b*NN + i];

  float tv[KK];
#pragma unroll
  for (int k = 0; k < KK; ++k) tv[k] = -INFINITY;

  for (int tile = 0; tile < 4; ++tile) {
    const int j0 = s*512 + tile*128;
    __syncthreads();
#pragma unroll
    for (int r = 0; r < 32; ++r) {
      const int linear = r*256 + t;
      const int c  = linear >> 7;
      const int jj = linear & 127;
      xjt[jj*68 + c] = xb[(size_t)c*NN + j0 + jj];
    }
    if (t < 128) xxj[t] = xx[b*NN + j0 + t];
    __syncthreads();

    for (int jj = 0; jj < 128; ++jj) {
      const float d = dot_d(xi, xjt + jj*68, xxi, xxj[jj]);
      // branchless sorted-desc insert (values only): 20 min + 20 max
#pragma unroll
      for (int q = KK-1; q >= 1; --q) tv[q] = fmaxf(fminf(tv[q-1], d), tv[q]);
      tv[0] = fmaxf(tv[0], d);
    }
  }
  const int row = b*NN + i;
#pragma unroll
  for (int k = 0; k < KK; ++k) tvals[(size_t)(s*KK + k)*BN + row] = tv[k];
}

// ---------------- K2b: 20th-largest of the 8x20 values -> t19 per row
__global__ __launch_bounds__(256) void k2b_merge(
    const float* __restrict__ tvals, float* __restrict__ t19) {
  const int row = blockIdx.x*256 + threadIdx.x;
  float tv[KK];
#pragma unroll
  for (int k = 0; k < KK; ++k) tv[k] = -INFINITY;
  for (int q = 0; q < SPLIT*KK; ++q) {
    const float d = tvals[(size_t)q*BN + row];
#pragma unroll
    for (int u = KK-1; u >= 1; --u) tv[u] = fmaxf(fminf(tv[u-1], d), tv[u]);
    tv[0] = fmaxf(tv[0], d);
  }
  t19[row] = tv[KK-1];
}

// ---------------- K2c: recompute d (bit-identical), collect indices >= t19
__global__ __launch_bounds__(256) void k2c_collect(
    const float* __restrict__ x, const float* __restrict__ xx,
    const float* __restrict__ t19, int* __restrict__ idxo,
    int* __restrict__ gcnt, int* __restrict__ ecnt, int* __restrict__ eqb) {
  __shared__ float xjt[128*68];
  __shared__ float xxj[128];
  const int b = blockIdx.z;
  const int s = blockIdx.y;
  const int t = threadIdx.x;
  const int i = blockIdx.x*256 + t;
  const float* xb = x + (size_t)b*CN;

  float4 xi[16];
#pragma unroll
  for (int c4 = 0; c4 < 16; ++c4) {
    xi[c4].x = xb[(size_t)(c4*4+0)*NN + i];
    xi[c4].y = xb[(size_t)(c4*4+1)*NN + i];
    xi[c4].z = xb[(size_t)(c4*4+2)*NN + i];
    xi[c4].w = xb[(size_t)(c4*4+3)*NN + i];
  }
  const float xxi = xx[b*NN + i];
  const int row = b*NN + i;
  const float thr = t19[row];

  for (int tile = 0; tile < 4; ++tile) {
    const int j0 = s*512 + tile*128;
    __syncthreads();
#pragma unroll
    for (int r = 0; r < 32; ++r) {
      const int linear = r*256 + t;
      const int c  = linear >> 7;
      const int jj = linear & 127;
      xjt[jj*68 + c] = xb[(size_t)c*NN + j0 + jj];
    }
    if (t < 128) xxj[t] = xx[b*NN + j0 + t];
    __syncthreads();

    for (int jj = 0; jj < 128; ++jj) {
      const float d = dot_d(xi, xjt + jj*68, xxi, xxj[jj]);
      if (d >= thr) {
        const int j = j0 + jj;
        if (d > thr) {
          const int p = atomicAdd(&gcnt[row], 1);
          idxo[(size_t)row*KK + p] = j;
        } else {
          const int e = atomicAdd(&ecnt[row], 1);
          if (e < EQCAP) eqb[(size_t)row*EQCAP + e] = j;
        }
      }
    }
  }
}

// ---------------- K2e: fill remaining slots with lowest-index ties
__global__ __launch_bounds__(256) void k2e_ties(
    const int* __restrict__ gcnt, const int* __restrict__ ecnt,
    const int* __restrict__ eqb, int* __restrict__ idxo) {
  const int row = blockIdx.x*256 + threadIdx.x;
  const int g = gcnt[row];
  const int e = min(ecnt[row], EQCAP);
  const int need = KK - g;
  int eqv[EQCAP];
#pragma unroll
  for (int u = 0; u < EQCAP; ++u) eqv[u] = (u < e) ? eqb[(size_t)row*EQCAP + u] : 0x7fffffff;
  int prev = -1;
#pragma unroll
  for (int r = 0; r < KK; ++r) {
    if (r < need) {
      int best = 0x7fffffff;
#pragma unroll
      for (int u = 0; u < EQCAP; ++u)
        if (eqv[u] > prev && eqv[u] < best) best = eqv[u];
      if (best == 0x7fffffff) best = 0;  // pathological safety
      idxo[(size_t)row*KK + g + r] = best;
      prev = best;
    }
  }
}

// ---------------- K3: gather neighbors, per-(b,n,o) max/min of h, BN sums
__global__ __launch_bounds__(256) void k3_gather(
    const float* __restrict__ p1, const float* __restrict__ p2,
    const int* __restrict__ idx, float* __restrict__ maxh,
    float* __restrict__ minh, double* __restrict__ sums) {
  const int t = threadIdx.x;
  const int g = t >> 6, o = t & 63;
  const int pn0 = blockIdx.x*64 + g*16;
  float sacc = 0.f, ssacc = 0.f;

  for (int p = 0; p < 16; ++p) {
    const int pn = pn0 + p;
    const int bbase = (pn >> 12) << 12;
    const float p1v = p1[(size_t)pn*64 + o];
    const int* ip = idx + (size_t)pn*KK;
    float mx = -INFINITY, mn = INFINITY;
#pragma unroll
    for (int k = 0; k < KK; ++k) {
      const int j = ip[k];
      const float p2v = p2[((size_t)(bbase + j))*64 + o];
      const float h = p1v + p2v;
      mx = fmaxf(mx, h); mn = fminf(mn, h);
      sacc += h; ssacc += h*h;
    }
    maxh[(size_t)pn*64 + o] = mx;
    minh[(size_t)pn*64 + o] = mn;
  }

  __shared__ float rs[256], rss[256];
  rs[t] = sacc; rss[t] = ssacc;
  __syncthreads();
  if (t < 64) {
    const double sv  = (double)rs[t]  + (double)rs[t+64]  + (double)rs[t+128]  + (double)rs[t+192];
    const double ssv = (double)rss[t] + (double)rss[t+64] + (double)rss[t+128] + (double)rss[t+192];
    atomicAdd(&sums[t], sv);
    atomicAdd(&sums[64 + t], ssv);
  }
}

// ---------------- K4: finalize BN, activation, transpose to (b,o,n)
__global__ __launch_bounds__(256) void k4_out(
    const float* __restrict__ maxh, const float* __restrict__ minh,
    const double* __restrict__ sums, const float* __restrict__ gamma,
    const float* __restrict__ beta, float* __restrict__ out) {
  __shared__ float sc[64], sh[64];
  __shared__ float lmax[64*65], lmin[64*65];
  const int b  = blockIdx.y;
  const int n0 = blockIdx.x * 64;
  const int t  = threadIdx.x;

  if (t < 64) {
    const double mean = sums[t] / CNT_TOTAL;
    const double var  = sums[64 + t] / CNT_TOTAL - mean*mean;
    const float scale = gamma[t] * (float)(1.0 / sqrt(var + EPSV));
    sc[t] = scale;
    sh[t] = beta[t] - (float)mean * scale;
  }
#pragma unroll
  for (int r = 0; r < 16; ++r) {
    const int linear = r*256 + t;
    const int o = linear & 63, pos = linear >> 6;
    const size_t gg = ((size_t)(b*NN) + n0 + pos)*64 + o;
    lmax[o*65 + pos] = maxh[gg];
    lmin[o*65 + pos] = minh[gg];
  }
  __syncthreads();

  const int nn = t & 63;
  const int obase = (t >> 6) * 16;
#pragma unroll
  for (int r = 0; r < 16; ++r) {
    const int o = obase + r;
    const float scale = sc[o], shift = sh[o];
    const float src = (scale >= 0.f) ? lmax[o*65 + nn] : lmin[o*65 + nn];
    float v = scale*src + shift;
    v = (v >= 0.f) ? v : NEG_SLOPE*v;
    out[(size_t)b*CO*NN + (size_t)o*NN + n0 + nn] = v;
  }
}

extern "C" void kernel_launch(void* const* d_in, const int* in_sizes, int n_in,
                              void* d_out, int out_size, void* d_ws, size_t ws_size,
                              hipStream_t stream) {
  const float* x     = (const float*)d_in[0];
  const float* W     = (const float*)d_in[1];
  const float* gamma = (const float*)d_in[2];
  const float* beta  = (const float*)d_in[3];
  float* out = (float*)d_out;
  char* ws = (char*)d_ws;

  float*  p1    = (float*)(ws + OFF_P1);
  float*  p2    = (float*)(ws + OFF_P2);
  float*  xx    = (float*)(ws + OFF_XX);
  int*    idx   = (int*)  (ws + OFF_IDX);
  float*  tvals = (float*)(ws + OFF_TVALS);
  float*  t19   = (float*)(ws + OFF_T19);
  int*    eqb   = (int*)  (ws + OFF_EQB);
  float*  maxh  = (float*)(ws + OFF_MAXH);
  float*  minh  = (float*)(ws + OFF_MINH);
  int*    gcnt  = (int*)  (ws + OFF_GCNT);
  int*    ecnt  = (int*)  (ws + OFF_ECNT);
  double* sums  = (double*)(ws + OFF_SUMS);

  hipMemsetAsync(ws + OFF_GCNT, 0, ZERO_BYTES, stream);

  k1_project <<<dim3(NN/64, BB), 256, 0, stream>>>(x, W, p1, p2, xx);
  k2a_vals   <<<dim3(NN/256, SPLIT, BB), 256, 0, stream>>>(x, xx, tvals);
  k2b_merge  <<<dim3(BN/256), 256, 0, stream>>>(tvals, t19);
  k2c_collect<<<dim3(NN/256, SPLIT, BB), 256, 0, stream>>>(x, xx, t19, idx, gcnt, ecnt, eqb);
  k2e_ties   <<<dim3(BN/256), 256, 0, stream>>>(gcnt, ecnt, eqb, idx);
  k3_gather  <<<dim3(BN/64), 256, 0, stream>>>(p1, p2, idx, maxh, minh, sums);
  k4_out     <<<dim3(NN/64, BB), 256, 0, stream>>>(maxh, minh, sums, gamma, beta, out);
}

// Round 4
// 719.944 us; speedup vs baseline: 1.9607x; 1.9607x over previous
//
#include <hip/hip_runtime.h>
#include <hip/hip_bf16.h>
#include <math.h>

// Problem constants
#define BB 8
#define CC 64
#define NN 4096
#define CO 64
#define KK 20
#define BN (BB*NN)           // 32768 rows
#define CN (CC*NN)           // 262144
#define EPSV 1e-5
#define NEG_SLOPE 0.2f
#define CNT_TOTAL 655360.0   // B*N*K
#define CAP 64
#define MARGIN 0.02f

typedef unsigned short U16;
typedef unsigned int u32;
typedef unsigned long long u64;
typedef __attribute__((ext_vector_type(8))) __bf16 bf16x8;
typedef __attribute__((ext_vector_type(16))) float f32x16;

// Workspace layout (bytes)
#define OFF_P1    ((size_t)0)          // BN*64 f32 = 8388608
#define OFF_P2    ((size_t)8388608)
#define OFF_XX    ((size_t)16777216)   // BN f32
#define OFF_IDX   ((size_t)16908288)   // BN*20 i32
#define OFF_XT    ((size_t)19529728)   // BN*64 f32 row-major points
#define OFF_XH    ((size_t)27918336)   // BN*64 bf16 hi
#define OFF_XL    ((size_t)32112640)   // BN*64 bf16 lo
#define OFF_TV    ((size_t)36306944)   // BN*4*20 f32 partial top-20 values
#define OFF_THR   ((size_t)46792704)   // BN f32
#define OFF_CAND  ((size_t)46923776)   // BN*CAP i32
#define OFF_CCNT  ((size_t)55312384)   // BN i32 (zeroed)
#define OFF_MAXH  ((size_t)55443456)
#define OFF_MINH  ((size_t)63832064)
#define OFF_SUMS  ((size_t)72220672)   // 128 f64 (zeroed)

// branchless sorted-desc insert (values only): 20 min + 20 max
#define NET_INS(dv) { _Pragma("unroll") \
  for (int q_ = KK-1; q_ >= 1; --q_) tv[q_] = fmaxf(fminf(tv[q_-1], (dv)), tv[q_]); \
  tv[0] = fmaxf(tv[0], (dv)); }

// ---------------- K0: transpose x -> XT f32 [B][N][64], split bf16 hi/lo
__global__ __launch_bounds__(256) void k0_repack(
    const float* __restrict__ x, float* __restrict__ XT,
    U16* __restrict__ XH, U16* __restrict__ XL) {
  __shared__ float tile[64*65];
  const int b = blockIdx.y, n0 = blockIdx.x*64, t = threadIdx.x;
#pragma unroll
  for (int r = 0; r < 16; ++r) {
    const int c = r*4 + (t>>6);
    const int nn = t & 63;
    tile[c*65 + nn] = x[(size_t)b*CN + (size_t)c*NN + n0 + nn];
  }
  __syncthreads();
  const int g = t>>6, pos = t&63;
  float v[16];
#pragma unroll
  for (int cc = 0; cc < 16; ++cc) v[cc] = tile[(g*16+cc)*65 + pos];
  const size_t base = ((size_t)(b*NN + n0 + pos))*64 + g*16;
#pragma unroll
  for (int u = 0; u < 4; ++u)
    *(float4*)(XT + base + u*4) = make_float4(v[u*4],v[u*4+1],v[u*4+2],v[u*4+3]);
  U16 hb[16], lb[16];
#pragma unroll
  for (int cc = 0; cc < 16; ++cc) {
    __hip_bfloat16 h = __float2bfloat16(v[cc]);
    float hf = __bfloat162float(h);
    __hip_bfloat16 lo = __float2bfloat16(v[cc] - hf);
    hb[cc] = reinterpret_cast<U16&>(h);
    lb[cc] = reinterpret_cast<U16&>(lo);
  }
  uint hw[8], lw[8];
#pragma unroll
  for (int u = 0; u < 8; ++u) {
    hw[u] = (uint)hb[2*u] | ((uint)hb[2*u+1] << 16);
    lw[u] = (uint)lb[2*u] | ((uint)lb[2*u+1] << 16);
  }
  *(uint4*)(XH + base)     = make_uint4(hw[0],hw[1],hw[2],hw[3]);
  *(uint4*)(XH + base + 8) = make_uint4(hw[4],hw[5],hw[6],hw[7]);
  *(uint4*)(XL + base)     = make_uint4(lw[0],lw[1],lw[2],lw[3]);
  *(uint4*)(XL + base + 8) = make_uint4(lw[4],lw[5],lw[6],lw[7]);
}

// ---------------- K1: projections p1=(W1-W2)x, p2=W2 x, xx=|x|^2 (unchanged)
__global__ __launch_bounds__(256) void k1_project(
    const float* __restrict__ x, const float* __restrict__ W,
    float* __restrict__ p1, float* __restrict__ p2, float* __restrict__ xx) {
  const int b  = blockIdx.y;
  const int n0 = blockIdx.x * 64;
  const int t  = threadIdx.x;
  const int pos = t & 63, og = t >> 6;
  const int n = n0 + pos;
  const float* xb = x + (size_t)b*CN + n;

  float a1[16], a2[16];
#pragma unroll
  for (int i = 0; i < 16; ++i) { a1[i] = 0.f; a2[i] = 0.f; }
  float xxa = 0.f;
#pragma unroll
  for (int c4 = 0; c4 < 16; ++c4) {
    float xv[4];
#pragma unroll
    for (int u = 0; u < 4; ++u) xv[u] = xb[(size_t)(c4*4+u)*NN];
    if (og == 0) xxa += xv[0]*xv[0] + xv[1]*xv[1] + xv[2]*xv[2] + xv[3]*xv[3];
#pragma unroll
    for (int oi = 0; oi < 16; ++oi) {
      const int o = og*16 + oi;
      const float4 w1 = *(const float4*)(W + o*128 + c4*4);
      const float4 w2 = *(const float4*)(W + o*128 + 64 + c4*4);
      a1[oi] += (w1.x - w2.x)*xv[0] + (w1.y - w2.y)*xv[1]
              + (w1.z - w2.z)*xv[2] + (w1.w - w2.w)*xv[3];
      a2[oi] += w2.x*xv[0] + w2.y*xv[1] + w2.z*xv[2] + w2.w*xv[3];
    }
  }
  float* p1o = p1 + ((size_t)(b*NN + n))*64 + og*16;
  float* p2o = p2 + ((size_t)(b*NN + n))*64 + og*16;
#pragma unroll
  for (int oi = 0; oi < 16; ++oi) { p1o[oi] = a1[oi]; p2o[oi] = a2[oi]; }
  if (og == 0) xx[b*NN + n] = xxa;
}

// ---------------- K2ab: MFMA Gram chunks; MODE0 = top-20 values, MODE1 = collect
template<int MODE>
__global__ __launch_bounds__(256) void k2ab(
    const U16* __restrict__ XH, const U16* __restrict__ XL,
    const float* __restrict__ xx, float* __restrict__ TV,
    const float* __restrict__ thr, int* __restrict__ ccnt,
    int* __restrict__ cand) {
  __shared__ float sc[256*36];   // scores [256 rows][32 cols], stride 36
  __shared__ float sxx[32];
  const int b = blockIdx.z, q = blockIdx.y, i0 = blockIdx.x*256;
  const int t = threadIdx.x, w = t>>6, l = t&63;
  const int rowg = b*NN + i0 + t;
  const size_t bnn = (size_t)b*NN;
  const int ch0 = 8*(l>>5);
  // wave w owns local rows [w*64, w*64+64) = msubs {2w, 2w+1}
  const size_t abase = (bnn + i0 + w*64 + (l&31))*64 + ch0;

  float tv[KK];
  float thrv = 0.f;
  if constexpr (MODE == 0) {
#pragma unroll
    for (int k = 0; k < KK; ++k) tv[k] = -INFINITY;
  } else {
    thrv = thr[rowg];
  }

  for (int chunk = 0; chunk < 32; ++chunk) {
    const int j0 = q*1024 + chunk*32;
    f32x16 acc[2];
#pragma unroll
    for (int ms = 0; ms < 2; ++ms)
#pragma unroll
      for (int r = 0; r < 16; ++r) acc[ms][r] = 0.f;

    const size_t bfb = (bnn + j0 + (l&31))*64 + ch0;
#pragma unroll
    for (int ks = 0; ks < 4; ++ks) {
      const bf16x8 Bh = *(const bf16x8*)(XH + bfb + ks*16);
      const bf16x8 Bl = *(const bf16x8*)(XL + bfb + ks*16);
#pragma unroll
      for (int ms = 0; ms < 2; ++ms) {
        const bf16x8 Ah = *(const bf16x8*)(XH + abase + ms*2048 + ks*16);
        const bf16x8 Al = *(const bf16x8*)(XL + abase + ms*2048 + ks*16);
        acc[ms] = __builtin_amdgcn_mfma_f32_32x32x16_bf16(Ah, Bh, acc[ms], 0,0,0);
        acc[ms] = __builtin_amdgcn_mfma_f32_32x32x16_bf16(Ah, Bl, acc[ms], 0,0,0);
        acc[ms] = __builtin_amdgcn_mfma_f32_32x32x16_bf16(Al, Bh, acc[ms], 0,0,0);
      }
    }
    __syncthreads();   // prev scan done -> safe to overwrite sc
    if (t < 32) sxx[t] = xx[bnn + j0 + t];
    // dump C/D: row=(r&3)+8*(r>>2)+4*(l>>5), col=l&31
#pragma unroll
    for (int ms = 0; ms < 2; ++ms)
#pragma unroll
      for (int r = 0; r < 16; ++r) {
        const int lrow = w*64 + ms*32 + (r&3) + 8*(r>>2) + 4*(l>>5);
        sc[lrow*36 + (l&31)] = acc[ms][r];
      }
    __syncthreads();
    // scan: thread t owns local row t; d' = 2*g - xx_j  (xx_i is a per-row const)
    const float* rowp = sc + t*36;
#pragma unroll
    for (int c4 = 0; c4 < 8; ++c4) {
      const float4 v  = *(const float4*)(rowp + c4*4);
      const float4 sx = *(const float4*)(sxx + c4*4);
      const float d0 = 2.f*v.x - sx.x, d1 = 2.f*v.y - sx.y;
      const float d2 = 2.f*v.z - sx.z, d3 = 2.f*v.w - sx.w;
      if constexpr (MODE == 0) {
        NET_INS(d0) NET_INS(d1) NET_INS(d2) NET_INS(d3)
      } else {
        const float dd[4] = {d0, d1, d2, d3};
#pragma unroll
        for (int e = 0; e < 4; ++e)
          if (dd[e] >= thrv) {
            const int pos = atomicAdd(&ccnt[rowg], 1);
            if (pos < CAP) cand[(size_t)rowg*CAP + pos] = j0 + c4*4 + e;
          }
      }
    }
  }
  if constexpr (MODE == 0) {
#pragma unroll
    for (int k = 0; k < KK; ++k) TV[((size_t)rowg*4 + q)*KK + k] = tv[k];
  }
}

// ---------------- K2b: 20th-largest of 4x20 partials -> thr = t19 - margin
__global__ __launch_bounds__(256) void k2b_thr(
    const float* __restrict__ TV, float* __restrict__ thr) {
  const int rowg = blockIdx.x*256 + threadIdx.x;
  float tv[KK];
#pragma unroll
  for (int k = 0; k < KK; ++k) tv[k] = -INFINITY;
  const float* p = TV + (size_t)rowg*80;
#pragma unroll
  for (int u = 0; u < 20; ++u) {
    const float4 v = *(const float4*)(p + u*4);
    NET_INS(v.x) NET_INS(v.y) NET_INS(v.z) NET_INS(v.w)
  }
  thr[rowg] = tv[KK-1] - MARGIN;
}

// ---------------- K2e: exact f32 dots on candidates, top-20 with numpy ties
__global__ __launch_bounds__(256) void k2e_exact(
    const float* __restrict__ XT, const float* __restrict__ xx,
    const int* __restrict__ ccnt, const int* __restrict__ cand,
    int* __restrict__ idxo) {
  const int t = threadIdx.x, w = t>>6, l = t&63;
  const int rowg = blockIdx.x*64 + w*16 + (l>>2);
  const int g = l & 3;
  const int bbase = (rowg >> 12) << 12;   // b*NN
  const float* xip = XT + (size_t)rowg*64 + g*16;
  const float4 xi0 = *(const float4*)(xip),   xi1 = *(const float4*)(xip+4);
  const float4 xi2 = *(const float4*)(xip+8), xi3 = *(const float4*)(xip+12);
  const float xxi = xx[rowg];
  const int Cr = min(ccnt[rowg], CAP);
  int cmax = Cr;
#pragma unroll
  for (int off = 1; off < 64; off <<= 1) cmax = max(cmax, __shfl_xor(cmax, off));
  u64 kv[KK];
#pragma unroll
  for (int k = 0; k < KK; ++k) kv[k] = 0ULL;

  for (int c = 0; c < cmax; ++c) {
    const bool valid = (c < Cr);
    const int jj = valid ? cand[(size_t)rowg*CAP + c] : 0;
    const float* xjp = XT + ((size_t)(bbase + jj))*64 + g*16;
    const float4 a  = *(const float4*)(xjp),   b4 = *(const float4*)(xjp+4);
    const float4 c4 = *(const float4*)(xjp+8), d4 = *(const float4*)(xjp+12);
    float p = xi0.x*a.x;
    p = fmaf(xi0.y, a.y, p);  p = fmaf(xi0.z, a.z, p);  p = fmaf(xi0.w, a.w, p);
    p = fmaf(xi1.x, b4.x, p); p = fmaf(xi1.y, b4.y, p); p = fmaf(xi1.z, b4.z, p); p = fmaf(xi1.w, b4.w, p);
    p = fmaf(xi2.x, c4.x, p); p = fmaf(xi2.y, c4.y, p); p = fmaf(xi2.z, c4.z, p); p = fmaf(xi2.w, c4.w, p);
    p = fmaf(xi3.x, d4.x, p); p = fmaf(xi3.y, d4.y, p); p = fmaf(xi3.z, d4.z, p); p = fmaf(xi3.w, d4.w, p);
    p += __shfl_xor(p, 1);
    p += __shfl_xor(p, 2);
    const float d = 2.f*p - xxi - xx[bbase + jj];
    const u32 s = __float_as_uint(d);
    const u32 k32 = (s & 0x80000000u) ? ~s : (s | 0x80000000u);
    u64 key = ((u64)k32 << 32) | (u64)(0xFFFFFFFFu - (u32)jj);
    if (!valid) key = 0ULL;
#pragma unroll
    for (int qq = KK-1; qq >= 1; --qq) {
      const u64 mn = (kv[qq-1] < key) ? kv[qq-1] : key;
      if (kv[qq] < mn) kv[qq] = mn;
    }
    if (kv[0] < key) kv[0] = key;
  }
  if (g == 0) {
#pragma unroll
    for (int k = 0; k < KK; ++k)
      idxo[(size_t)rowg*KK + k] = (int)(0xFFFFFFFFu - (u32)(kv[k] & 0xFFFFFFFFu));
  }
}

// ---------------- K3: gather neighbors, per-(b,n,o) max/min of h, BN sums
__global__ __launch_bounds__(256) void k3_gather(
    const float* __restrict__ p1, const float* __restrict__ p2,
    const int* __restrict__ idx, float* __restrict__ maxh,
    float* __restrict__ minh, double* __restrict__ sums) {
  const int t = threadIdx.x;
  const int g = t >> 6, o = t & 63;
  const int pn0 = blockIdx.x*64 + g*16;
  float sacc = 0.f, ssacc = 0.f;

  for (int p = 0; p < 16; ++p) {
    const int pn = pn0 + p;
    const int bbase = (pn >> 12) << 12;
    const float p1v = p1[(size_t)pn*64 + o];
    const int* ip = idx + (size_t)pn*KK;
    float mx = -INFINITY, mn = INFINITY;
#pragma unroll
    for (int k = 0; k < KK; ++k) {
      const int j = ip[k];
      const float p2v = p2[((size_t)(bbase + j))*64 + o];
      const float h = p1v + p2v;
      mx = fmaxf(mx, h); mn = fminf(mn, h);
      sacc += h; ssacc += h*h;
    }
    maxh[(size_t)pn*64 + o] = mx;
    minh[(size_t)pn*64 + o] = mn;
  }

  __shared__ float rs[256], rss[256];
  rs[t] = sacc; rss[t] = ssacc;
  __syncthreads();
  if (t < 64) {
    const double sv  = (double)rs[t]  + (double)rs[t+64]  + (double)rs[t+128]  + (double)rs[t+192];
    const double ssv = (double)rss[t] + (double)rss[t+64] + (double)rss[t+128] + (double)rss[t+192];
    atomicAdd(&sums[t], sv);
    atomicAdd(&sums[64 + t], ssv);
  }
}

// ---------------- K4: finalize BN, activation, transpose to (b,o,n)
__global__ __launch_bounds__(256) void k4_out(
    const float* __restrict__ maxh, const float* __restrict__ minh,
    const double* __restrict__ sums, const float* __restrict__ gamma,
    const float* __restrict__ beta, float* __restrict__ out) {
  __shared__ float sc_[64], sh_[64];
  __shared__ float lmax[64*65], lmin[64*65];
  const int b  = blockIdx.y;
  const int n0 = blockIdx.x * 64;
  const int t  = threadIdx.x;

  if (t < 64) {
    const double mean = sums[t] / CNT_TOTAL;
    const double var  = sums[64 + t] / CNT_TOTAL - mean*mean;
    const float scale = gamma[t] * (float)(1.0 / sqrt(var + EPSV));
    sc_[t] = scale;
    sh_[t] = beta[t] - (float)mean * scale;
  }
#pragma unroll
  for (int r = 0; r < 16; ++r) {
    const int linear = r*256 + t;
    const int o = linear & 63, pos = linear >> 6;
    const size_t gg = ((size_t)(b*NN) + n0 + pos)*64 + o;
    lmax[o*65 + pos] = maxh[gg];
    lmin[o*65 + pos] = minh[gg];
  }
  __syncthreads();

  const int nn = t & 63;
  const int obase = (t >> 6) * 16;
#pragma unroll
  for (int r = 0; r < 16; ++r) {
    const int o = obase + r;
    const float scale = sc_[o], shift = sh_[o];
    const float src = (scale >= 0.f) ? lmax[o*65 + nn] : lmin[o*65 + nn];
    float v = scale*src + shift;
    v = (v >= 0.f) ? v : NEG_SLOPE*v;
    out[(size_t)b*CO*NN + (size_t)o*NN + n0 + nn] = v;
  }
}

extern "C" void kernel_launch(void* const* d_in, const int* in_sizes, int n_in,
                              void* d_out, int out_size, void* d_ws, size_t ws_size,
                              hipStream_t stream) {
  const float* x     = (const float*)d_in[0];
  const float* W     = (const float*)d_in[1];
  const float* gamma = (const float*)d_in[2];
  const float* beta  = (const float*)d_in[3];
  float* out = (float*)d_out;
  char* ws = (char*)d_ws;

  float*  p1   = (float*)(ws + OFF_P1);
  float*  p2   = (float*)(ws + OFF_P2);
  float*  xx   = (float*)(ws + OFF_XX);
  int*    idx  = (int*)  (ws + OFF_IDX);
  float*  XT   = (float*)(ws + OFF_XT);
  U16*    XH   = (U16*)  (ws + OFF_XH);
  U16*    XL   = (U16*)  (ws + OFF_XL);
  float*  TV   = (float*)(ws + OFF_TV);
  float*  thr  = (float*)(ws + OFF_THR);
  int*    cand = (int*)  (ws + OFF_CAND);
  int*    ccnt = (int*)  (ws + OFF_CCNT);
  float*  maxh = (float*)(ws + OFF_MAXH);
  float*  minh = (float*)(ws + OFF_MINH);
  double* sums = (double*)(ws + OFF_SUMS);

  hipMemsetAsync(ws + OFF_CCNT, 0, BN*sizeof(int), stream);
  hipMemsetAsync(ws + OFF_SUMS, 0, 128*sizeof(double), stream);

  k0_repack <<<dim3(NN/64, BB), 256, 0, stream>>>(x, XT, XH, XL);
  k1_project<<<dim3(NN/64, BB), 256, 0, stream>>>(x, W, p1, p2, xx);
  k2ab<0>   <<<dim3(NN/256, 4, BB), 256, 0, stream>>>(XH, XL, xx, TV, thr, ccnt, cand);
  k2b_thr   <<<dim3(BN/256), 256, 0, stream>>>(TV, thr);
  k2ab<1>   <<<dim3(NN/256, 4, BB), 256, 0, stream>>>(XH, XL, xx, TV, thr, ccnt, cand);
  k2e_exact <<<dim3(BN/64), 256, 0, stream>>>(XT, xx, ccnt, cand, idx);
  k3_gather <<<dim3(BN/64), 256, 0, stream>>>(p1, p2, idx, maxh, minh, sums);
  k4_out    <<<dim3(NN/64, BB), 256, 0, stream>>>(maxh, minh, sums, gamma, beta, out);
}